// Round 10
// baseline (241.345 us; speedup 1.0000x reference)
//
#include <hip/hip_runtime.h>

// 3-level Haar cascade, single dispatch, role-split by blockIdx.y.
//  by in [0,96):   K1 path — c in [8,32), level-1 only (75% of traffic).
//                  Fat threads: 8x f4 nt-loads (128B/lane) -> 8x f4 nt-stores.
//  by in [96,128): K2 path — c in [0,8), fused L1+L2+L3 in registers.
// Routing (verified absmax=0 rounds 1/5/7/9):
//   L1: ch=4c+s; c>=8 -> high1 ch 4(c-8)+s.
//   L2: c>=2 -> high2 ch 16(c-2)+4s+s2.
//   L3: ch3=64c+16s+4s2+s3; ch3<32 -> low3 (x2) else high3 ch3-32.

typedef float f4 __attribute__((ext_vector_type(4)));
typedef float f2 __attribute__((ext_vector_type(2)));

#define HAAR(a, b_, c_, d, o0, o1, o2, o3)       \
    o0 = (a + b_ + c_ + d) * 0.5f;               \
    o1 = (a - b_ + c_ - d) * 0.5f;               \
    o2 = (a + b_ - c_ - d) * 0.5f;               \
    o3 = (a - b_ - c_ + d) * 0.5f;

__global__ __launch_bounds__(256) void haar_all(
    const float* __restrict__ x,      // [4,32,512,512]
    float* __restrict__ high1,        // [4,96,256,256]
    float* __restrict__ high2,        // [4,96,128,128]
    float* __restrict__ high3,        // [4,96,64,64]
    float* __restrict__ low3a,        // [4,32,64,64]
    float* __restrict__ low3b)
{
    const int tid = threadIdx.x;
    const int by  = blockIdx.y;

    if (by < 96) {
        // ---------------- K1: c in [8,32), fat streaming ----------------
        const int c24 = by % 24;
        const int b   = by / 24;
        const int oh  = (blockIdx.x << 3) | (tid >> 5);   // output row 0..255
        const int oc8 = tid & 31;                          // 8 out cols per thread

        const float* base = x + ((size_t)(b * 32 + c24 + 8) * 512 + (size_t)(2 * oh)) * 512
                              + (size_t)(16 * oc8);
        f4 r0[4], r1[4];
        #pragma unroll
        for (int q = 0; q < 4; ++q)
            r0[q] = __builtin_nontemporal_load((const f4*)(base + 4 * q));
        #pragma unroll
        for (int q = 0; q < 4; ++q)
            r1[q] = __builtin_nontemporal_load((const f4*)(base + 512 + 4 * q));

        float LL[8], LH[8], HL[8], HH[8];
        #pragma unroll
        for (int q = 0; q < 4; ++q) {
            HAAR(r0[q].x, r0[q].y, r1[q].x, r1[q].y,
                 LL[2 * q], LH[2 * q], HL[2 * q], HH[2 * q]);
            HAAR(r0[q].z, r0[q].w, r1[q].z, r1[q].w,
                 LL[2 * q + 1], LH[2 * q + 1], HL[2 * q + 1], HH[2 * q + 1]);
        }

        float* hp = high1 + ((size_t)b * 96 + (size_t)(4 * c24)) * (256 * 256)
                          + (size_t)oh * 256 + (size_t)(8 * oc8);
        f4 v;
        v = (f4){LL[0], LL[1], LL[2], LL[3]};  __builtin_nontemporal_store(v, (f4*)(hp + 0 * 65536));
        v = (f4){LL[4], LL[5], LL[6], LL[7]};  __builtin_nontemporal_store(v, (f4*)(hp + 0 * 65536 + 4));
        v = (f4){LH[0], LH[1], LH[2], LH[3]};  __builtin_nontemporal_store(v, (f4*)(hp + 1 * 65536));
        v = (f4){LH[4], LH[5], LH[6], LH[7]};  __builtin_nontemporal_store(v, (f4*)(hp + 1 * 65536 + 4));
        v = (f4){HL[0], HL[1], HL[2], HL[3]};  __builtin_nontemporal_store(v, (f4*)(hp + 2 * 65536));
        v = (f4){HL[4], HL[5], HL[6], HL[7]};  __builtin_nontemporal_store(v, (f4*)(hp + 2 * 65536 + 4));
        v = (f4){HH[0], HH[1], HH[2], HH[3]};  __builtin_nontemporal_store(v, (f4*)(hp + 3 * 65536));
        v = (f4){HH[4], HH[5], HH[6], HH[7]};  __builtin_nontemporal_store(v, (f4*)(hp + 3 * 65536 + 4));
        return;
    }

    // ---------------- K2: c in [0,8), fused 3 levels ----------------
    if (blockIdx.x >= 16) return;      // K2 uses only 16 x-tiles
    const int bc    = by - 96;         // b*8 + c
    const int c     = bc & 7;
    const int b     = bc >> 3;
    const int tx    = tid & 63;
    const int ty    = tid >> 6;
    const int tileY = blockIdx.x;

    float w1[4][4][4];
    {
        const float* base = x + ((size_t)(b * 32 + c) * 512 + (size_t)(tileY * 32 + ty * 8)) * 512
                              + (size_t)tx * 8;
        #pragma unroll
        for (int i = 0; i < 4; ++i) {
            f4 r0a = __builtin_nontemporal_load((const f4*)(base + (size_t)(2 * i) * 512));
            f4 r0b = __builtin_nontemporal_load((const f4*)(base + (size_t)(2 * i) * 512 + 4));
            f4 r1a = __builtin_nontemporal_load((const f4*)(base + (size_t)(2 * i + 1) * 512));
            f4 r1b = __builtin_nontemporal_load((const f4*)(base + (size_t)(2 * i + 1) * 512 + 4));
            HAAR(r0a.x, r0a.y, r1a.x, r1a.y, w1[0][i][0], w1[1][i][0], w1[2][i][0], w1[3][i][0]);
            HAAR(r0a.z, r0a.w, r1a.z, r1a.w, w1[0][i][1], w1[1][i][1], w1[2][i][1], w1[3][i][1]);
            HAAR(r0b.x, r0b.y, r1b.x, r1b.y, w1[0][i][2], w1[1][i][2], w1[2][i][2], w1[3][i][2]);
            HAAR(r0b.z, r0b.w, r1b.z, r1b.w, w1[0][i][3], w1[1][i][3], w1[2][i][3], w1[3][i][3]);
        }
    }

    float w2[16][2][2];
    #pragma unroll
    for (int s = 0; s < 4; ++s)
        #pragma unroll
        for (int i = 0; i < 2; ++i)
            #pragma unroll
            for (int j = 0; j < 2; ++j) {
                float a  = w1[s][2 * i][2 * j];
                float bb = w1[s][2 * i][2 * j + 1];
                float cc = w1[s][2 * i + 1][2 * j];
                float dd = w1[s][2 * i + 1][2 * j + 1];
                HAAR(a, bb, cc, dd, w2[4 * s + 0][i][j], w2[4 * s + 1][i][j],
                                    w2[4 * s + 2][i][j], w2[4 * s + 3][i][j]);
            }

    if (c >= 2) {
        float* hp = high2 + ((size_t)b * 96 + (size_t)(16 * (c - 2))) * (128 * 128)
                          + (size_t)(tileY * 8 + ty * 2) * 128 + (size_t)tx * 2;
        #pragma unroll
        for (int j2 = 0; j2 < 16; ++j2)
            #pragma unroll
            for (int i = 0; i < 2; ++i) {
                f2 v = {w2[j2][i][0], w2[j2][i][1]};
                __builtin_nontemporal_store(v, (f2*)(hp + (size_t)j2 * (128 * 128) + i * 128));
            }
        return;
    }

    const size_t p3  = 64 * 64;
    const size_t sp3 = (size_t)(tileY * 4 + ty) * 64 + (size_t)tx;
    #pragma unroll
    for (int j2 = 0; j2 < 16; ++j2) {
        float a  = w2[j2][0][0];
        float bb = w2[j2][0][1];
        float cc = w2[j2][1][0];
        float dd = w2[j2][1][1];
        float v0, v1, v2, v3;
        HAAR(a, bb, cc, dd, v0, v1, v2, v3);
        float v[4] = {v0, v1, v2, v3};
        #pragma unroll
        for (int s3 = 0; s3 < 4; ++s3) {
            int ch = 64 * c + 4 * j2 + s3;
            if (ch < 32) {
                __builtin_nontemporal_store(v[s3], low3a + ((size_t)b * 32 + ch) * p3 + sp3);
                __builtin_nontemporal_store(v[s3], low3b + ((size_t)b * 32 + ch) * p3 + sp3);
            } else {
                __builtin_nontemporal_store(v[s3], high3 + ((size_t)b * 96 + (ch - 32)) * p3 + sp3);
            }
        }
    }
}

extern "C" void kernel_launch(void* const* d_in, const int* in_sizes, int n_in,
                              void* d_out, int out_size, void* d_ws, size_t ws_size,
                              hipStream_t stream) {
    const float* x = (const float*)d_in[0];
    float* out = (float*)d_out;

    const size_t n_low3  = (size_t)4 * 32 * 64 * 64;
    const size_t n_high1 = (size_t)4 * 96 * 256 * 256;
    const size_t n_high2 = (size_t)4 * 96 * 128 * 128;
    const size_t n_high3 = (size_t)4 * 96 * 64 * 64;

    float* low3a = out;
    float* high1 = out + n_low3;
    float* high2 = high1 + n_high1;
    float* high3 = high2 + n_high2;
    float* low3b = high3 + n_high3;

    // y: [0,96) K1 (b*24+(c-8)), [96,128) K2 (b*8+c). x: 32 (K2 uses 16).
    haar_all<<<dim3(32, 128), 256, 0, stream>>>(x, high1, high2, high3, low3a, low3b);
}